// Round 4
// baseline (210.983 us; speedup 1.0000x reference)
//
#include <hip/hip_runtime.h>

#define NB  32
#define IDF 768
#define SLN 128
#define QLN 1024

typedef __bf16 v8bf __attribute__((ext_vector_type(8)));
typedef __bf16 v4bf __attribute__((ext_vector_type(4)));
typedef float  v4f  __attribute__((ext_vector_type(4)));

#define MFMA16 __builtin_amdgcn_mfma_f32_16x16x32_bf16

__device__ __forceinline__ void split2(float x, __bf16& h, __bf16& l) {
  h = (__bf16)x;
  l = (__bf16)(x - (float)h);
}

// -----------------------------------------------------------------------------
// K0: W [768*768] f32 -> Wh, Wl bf16 (same layout). 576 blocks x 256 thr x 4.
// -----------------------------------------------------------------------------
__global__ __launch_bounds__(256) void prep_w(const float* __restrict__ W,
                                              __bf16* __restrict__ Wh,
                                              __bf16* __restrict__ Wl) {
  int idx = blockIdx.x * 1024 + threadIdx.x * 4;
  float4 v = *(const float4*)(W + idx);
  float vals[4] = {v.x, v.y, v.z, v.w};
  v4bf h, l;
#pragma unroll
  for (int e = 0; e < 4; ++e) {
    __bf16 hh, ll;
    split2(vals[e], hh, ll);
    h[e] = hh;
    l[e] = ll;
  }
  *(v4bf*)(Wh + idx) = h;
  *(v4bf*)(Wl + idx) = l;
}

// -----------------------------------------------------------------------------
// K1 proj: D[s][o] = sum_c ctx[b][c][s] * W[o][c]
// tile 128s x 32o, grid (24, 32) = 768 blocks, 4 waves; wave w: rows w*32..+32
// (2 fr), cols both fc. ctx staged f32 (vector float2, 2-way banks), split in
// regs. W hi/lo from global (L2-resident). Outputs STh/STl [b][s][768] and
// Shv [b][i][s].
// -----------------------------------------------------------------------------
__global__ __launch_bounds__(256) void proj_k(const float* __restrict__ ctx,
                                              const __bf16* __restrict__ Wh,
                                              const __bf16* __restrict__ Wl,
                                              __bf16* __restrict__ STh,
                                              __bf16* __restrict__ STl,
                                              __bf16* __restrict__ Shv) {
  const int b = blockIdx.y, o0 = blockIdx.x * 32;
  const int t = threadIdx.x, w = t >> 6, lane = t & 63;
  const int lr = lane & 15, lg = lane >> 4;
  __shared__ __align__(16) float ct[32][130];  // [c-local][s] f32
  v4f acc[2][2];
#pragma unroll
  for (int fr = 0; fr < 2; ++fr)
#pragma unroll
    for (int fc = 0; fc < 2; ++fc) acc[fr][fc] = (v4f){0.f, 0.f, 0.f, 0.f};

  for (int c0 = 0; c0 < IDF; c0 += 32) {
    __syncthreads();
#pragma unroll
    for (int j = 0; j < 8; ++j) {  // 2048 float2, 8 per thread
      int u = j * 256 + t, c = u >> 6, s2 = u & 63;
      *(float2*)&ct[c][s2 * 2] =
          *(const float2*)(ctx + ((size_t)b * IDF + c0 + c) * SLN + s2 * 2);
    }
    __syncthreads();
    v8bf bh[2], bl[2];
#pragma unroll
    for (int fc = 0; fc < 2; ++fc) {
      size_t off = (size_t)(o0 + fc * 16 + lr) * IDF + c0 + lg * 8;
      bh[fc] = *(const v8bf*)(Wh + off);
      bl[fc] = *(const v8bf*)(Wl + off);
    }
#pragma unroll
    for (int fr = 0; fr < 2; ++fr) {
      const int s = w * 32 + fr * 16 + lr;
      v8bf ah, al;
#pragma unroll
      for (int e = 0; e < 8; ++e) {  // 2-way banks (stride 130 words)
        __bf16 h, l;
        split2(ct[lg * 8 + e][s], h, l);
        ah[e] = h;
        al[e] = l;
      }
#pragma unroll
      for (int fc = 0; fc < 2; ++fc) {
        acc[fr][fc] = MFMA16(ah, bh[fc], acc[fr][fc], 0, 0, 0);
        acc[fr][fc] = MFMA16(ah, bl[fc], acc[fr][fc], 0, 0, 0);
        acc[fr][fc] = MFMA16(al, bh[fc], acc[fr][fc], 0, 0, 0);
      }
    }
  }
#pragma unroll
  for (int fr = 0; fr < 2; ++fr)
#pragma unroll
    for (int fc = 0; fc < 2; ++fc) {
      const int o = o0 + fc * 16 + lr;
      __bf16 hp[4];
#pragma unroll
      for (int r = 0; r < 4; ++r) {
        int s = w * 32 + fr * 16 + lg * 4 + r;
        __bf16 h, l;
        split2(acc[fr][fc][r], h, l);
        STh[((size_t)b * SLN + s) * IDF + o] = h;
        STl[((size_t)b * SLN + s) * IDF + o] = l;
        hp[r] = h;
      }
      *(v4bf*)(Shv + ((size_t)b * IDF + o) * SLN + w * 32 + fr * 16 + lg * 4) =
          (v4bf){hp[0], hp[1], hp[2], hp[3]};
    }
}

// -----------------------------------------------------------------------------
// K2 qkpv (fused): per (b, 64q): QK -> mask -> softmax -> attn_out + P(lds,
// XOR-swizzled) -> PV -> wc. A(QK) = ST hi/lo from global L2; B(QK) = input
// tile staged f32 + reg-split. PV: A = Shv global, B = P fragments hoisted.
// -----------------------------------------------------------------------------
__global__ __launch_bounds__(256) void qkpv_k(const float* __restrict__ input,
                                              const __bf16* __restrict__ STh,
                                              const __bf16* __restrict__ STl,
                                              const __bf16* __restrict__ Shv,
                                              const int* __restrict__ mask,
                                              float* __restrict__ wc,
                                              float* __restrict__ attn_out) {
  const int b = blockIdx.y, q0 = blockIdx.x * 64;
  const int t = threadIdx.x, w = t >> 6, lane = t & 63;
  const int lr = lane & 15, lg = lane >> 4;
  __shared__ __align__(16) float ti[64][66];    // input tile [i-local][q]
  __shared__ __align__(16) __bf16 Pl[64 * 128]; // P^T rows 256B, XOR-swizzled
  __shared__ float msk[SLN];
  if (t < SLN) msk[t] = -10000.0f * (float)mask[b * SLN + t];

  v4f acc[8];
#pragma unroll
  for (int fr = 0; fr < 8; ++fr) acc[fr] = (v4f){0.f, 0.f, 0.f, 0.f};

  for (int it = 0; it < 12; ++it) {
    const int i0 = it * 64;
    __syncthreads();
#pragma unroll
    for (int j = 0; j < 8; ++j) {  // 2048 float2 stage, coalesced 256B rows
      int u = j * 256 + t, row = u >> 5, q2 = u & 31;
      *(float2*)&ti[row][q2 * 2] =
          *(const float2*)(input + ((size_t)b * IDF + i0 + row) * QLN + q0 + q2 * 2);
    }
    __syncthreads();
#pragma unroll
    for (int ks = 0; ks < 2; ++ks) {
      v8bf bh, bl;
#pragma unroll
      for (int e = 0; e < 8; ++e) {  // 2-way banks (stride 66 words)
        __bf16 h, l;
        split2(ti[ks * 32 + lg * 8 + e][w * 16 + lr], h, l);
        bh[e] = h;
        bl[e] = l;
      }
#pragma unroll
      for (int fr = 0; fr < 8; ++fr) {
        size_t off = ((size_t)b * SLN + fr * 16 + lr) * IDF + i0 + ks * 32 + lg * 8;
        v8bf ah = *(const v8bf*)(STh + off);
        v8bf al = *(const v8bf*)(STl + off);
        acc[fr] = MFMA16(ah, bh, acc[fr], 0, 0, 0);
        acc[fr] = MFMA16(ah, bl, acc[fr], 0, 0, 0);
        acc[fr] = MFMA16(al, bh, acc[fr], 0, 0, 0);
      }
    }
  }

  // softmax over s (lane holds 32 s for one q; reduce over lg via shfl 16/32)
  const int q = q0 + w * 16 + lr;
  float mx = -3.0e38f;
#pragma unroll
  for (int fr = 0; fr < 8; ++fr)
#pragma unroll
    for (int r = 0; r < 4; ++r) {
      acc[fr][r] += msk[fr * 16 + lg * 4 + r];
      mx = fmaxf(mx, acc[fr][r]);
    }
  mx = fmaxf(mx, __shfl_xor(mx, 16));
  mx = fmaxf(mx, __shfl_xor(mx, 32));
  float sum = 0.f;
#pragma unroll
  for (int fr = 0; fr < 8; ++fr)
#pragma unroll
    for (int r = 0; r < 4; ++r) {
      float e = __expf(acc[fr][r] - mx);
      acc[fr][r] = e;
      sum += e;
    }
  sum += __shfl_xor(sum, 16);
  sum += __shfl_xor(sum, 32);
  const float inv = 1.0f / sum;

  const int qloc = w * 16 + lr;
#pragma unroll
  for (int fr = 0; fr < 8; ++fr) {
    __bf16 hp[4];
#pragma unroll
    for (int r = 0; r < 4; ++r) {
      float p = acc[fr][r] * inv;
      attn_out[((size_t)b * SLN + fr * 16 + lg * 4 + r) * QLN + q] = p;
      hp[r] = (__bf16)p;
    }
    int inrow = (32 * fr + 8 * lg) ^ ((qloc & 7) << 4);  // swizzled 8B slot
    *(v4bf*)((char*)Pl + qloc * 256 + inrow) = (v4bf){hp[0], hp[1], hp[2], hp[3]};
  }
  __syncthreads();

  // PV: hoist all P fragments (read with same swizzle; 2-way banks)
  v8bf pb[4][4];
#pragma unroll
  for (int fc = 0; fc < 4; ++fc)
#pragma unroll
    for (int ks = 0; ks < 4; ++ks) {
      int qr = fc * 16 + lr;
      int inrow = (64 * ks + 16 * lg) ^ ((qr & 7) << 4);
      pb[fc][ks] = *(const v8bf*)((const char*)Pl + qr * 256 + inrow);
    }
#pragma unroll 2
  for (int it = 0; it < 12; ++it) {
    const int i0 = it * 64;
    v4f a2[4];
#pragma unroll
    for (int fc = 0; fc < 4; ++fc) a2[fc] = (v4f){0.f, 0.f, 0.f, 0.f};
#pragma unroll
    for (int ks = 0; ks < 4; ++ks) {
      v8bf av = *(const v8bf*)(Shv + ((size_t)b * IDF + i0 + w * 16 + lr) * SLN +
                               ks * 32 + lg * 8);
#pragma unroll
      for (int fc = 0; fc < 4; ++fc)
        a2[fc] = MFMA16(av, pb[fc][ks], a2[fc], 0, 0, 0);
    }
#pragma unroll
    for (int fc = 0; fc < 4; ++fc)
#pragma unroll
      for (int r = 0; r < 4; ++r)
        wc[((size_t)b * IDF + i0 + w * 16 + lg * 4 + r) * QLN + q0 + fc * 16 + lr] =
            a2[fc][r];
  }
}

// -----------------------------------------------------------------------------
extern "C" void kernel_launch(void* const* d_in, const int* in_sizes, int n_in,
                              void* d_out, int out_size, void* d_ws, size_t ws_size,
                              hipStream_t stream) {
  const float* input   = (const float*)d_in[0];  // [B, IDF, 32, 32]
  const float* context = (const float*)d_in[1];  // [B, CDF, SL]
  const int*   mask    = (const int*)d_in[2];    // [B, SL]
  const float* w_conv  = (const float*)d_in[3];  // [IDF, CDF]

  float* out      = (float*)d_out;
  float* wc       = out;                          // [B, IDF, QL]
  float* attn_out = out + (size_t)NB * IDF * QLN; // [B, SL, QL]

  // ws: Wh, Wl [768*768], STh, STl [b][s][768], Shv [b][i][s]
  // bytes = (2*589824 + 3*3145728)*2 = 21,233,664
  __bf16* wsb = (__bf16*)d_ws;
  const size_t WE = (size_t)IDF * IDF;        // 589,824
  const size_t SE = (size_t)NB * SLN * IDF;   // 3,145,728
  __bf16* Wh  = wsb;
  __bf16* Wl  = Wh + WE;
  __bf16* STh = Wl + WE;
  __bf16* STl = STh + SE;
  __bf16* Shv = STl + SE;

  prep_w<<<576, 256, 0, stream>>>(w_conv, Wh, Wl);
  proj_k<<<dim3(24, NB), 256, 0, stream>>>(context, Wh, Wl, STh, STl, Shv);
  qkpv_k<<<dim3(16, NB), 256, 0, stream>>>(input, STh, STl, Shv, mask, wc, attn_out);
}

// Round 5
// 143.890 us; speedup vs baseline: 1.4663x; 1.4663x over previous
//
#include <hip/hip_runtime.h>

#define NB  32
#define IDF 768
#define SLN 128
#define QLN 1024
#define NT  24   // IDF/32 k-tiles

typedef __bf16 v8bf __attribute__((ext_vector_type(8)));
typedef __bf16 v4bf __attribute__((ext_vector_type(4)));
typedef float  v4f  __attribute__((ext_vector_type(4)));

#define MFMA16 __builtin_amdgcn_mfma_f32_16x16x32_bf16

__device__ __forceinline__ void split2(float x, __bf16& h, __bf16& l) {
  h = (__bf16)x;
  l = (__bf16)(x - (float)h);
}

// -----------------------------------------------------------------------------
// K0: W [768*768] f32 -> Wh, Wl bf16 (same layout).
// -----------------------------------------------------------------------------
__global__ __launch_bounds__(256) void prep_w(const float* __restrict__ W,
                                              __bf16* __restrict__ Wh,
                                              __bf16* __restrict__ Wl) {
  int idx = blockIdx.x * 1024 + threadIdx.x * 4;
  float4 v = *(const float4*)(W + idx);
  float vals[4] = {v.x, v.y, v.z, v.w};
  v4bf h, l;
#pragma unroll
  for (int e = 0; e < 4; ++e) {
    __bf16 hh, ll;
    split2(vals[e], hh, ll);
    h[e] = hh;
    l[e] = ll;
  }
  *(v4bf*)(Wh + idx) = h;
  *(v4bf*)(Wl + idx) = l;
}

// -----------------------------------------------------------------------------
// K1 proj: D[s][o] = sum_c ctx[b][c][s] * W[o][c].  Tile 128s x 32o, grid
// (24,32)=768 blocks, 4 waves. Reg-prefetch: ctx tile t+1 and W frags t+1
// loaded during compute(t). ctx in LDS f32 [32][130] (float2 writes, 2-way
// reads); split to bf16 in regs. Outputs STh/STl [b][s][768], Shv [b][i][s].
// -----------------------------------------------------------------------------
__global__ __launch_bounds__(256) void proj_k(const float* __restrict__ ctx,
                                              const __bf16* __restrict__ Wh,
                                              const __bf16* __restrict__ Wl,
                                              __bf16* __restrict__ STh,
                                              __bf16* __restrict__ STl,
                                              __bf16* __restrict__ Shv) {
  const int b = blockIdx.y, o0 = blockIdx.x * 32;
  const int t = threadIdx.x, w = t >> 6, lane = t & 63;
  const int lr = lane & 15, lg = lane >> 4;
  __shared__ __align__(16) float ct[32][130];
  v4f acc[2][2];
#pragma unroll
  for (int fr = 0; fr < 2; ++fr)
#pragma unroll
    for (int fc = 0; fc < 2; ++fc) acc[fr][fc] = (v4f){0.f, 0.f, 0.f, 0.f};

  const int crow = t >> 6;       // + j*4
  const int ccol = (t & 63) * 2;
  const float* cbase = ctx + ((size_t)b * IDF + crow) * SLN + ccol;

  float2 rc[8];
  v8bf bhc[2], blc[2];
  // prologue: tile 0
#pragma unroll
  for (int j = 0; j < 8; ++j)
    rc[j] = *(const float2*)(cbase + (size_t)(j * 4) * SLN);
#pragma unroll
  for (int fc = 0; fc < 2; ++fc) {
    size_t off = (size_t)(o0 + fc * 16 + lr) * IDF + lg * 8;
    bhc[fc] = *(const v8bf*)(Wh + off);
    blc[fc] = *(const v8bf*)(Wl + off);
  }

  for (int it = 0; it < NT; ++it) {
    __syncthreads();
#pragma unroll
    for (int j = 0; j < 8; ++j)
      *(float2*)&ct[j * 4 + crow][ccol] = rc[j];

    float2 nc[8];
    v8bf bhn[2], bln[2];
    if (it + 1 < NT) {
      const int c0n = (it + 1) * 32;
#pragma unroll
      for (int j = 0; j < 8; ++j)
        nc[j] = *(const float2*)(cbase + (size_t)(c0n + j * 4) * SLN);
#pragma unroll
      for (int fc = 0; fc < 2; ++fc) {
        size_t off = (size_t)(o0 + fc * 16 + lr) * IDF + c0n + lg * 8;
        bhn[fc] = *(const v8bf*)(Wh + off);
        bln[fc] = *(const v8bf*)(Wl + off);
      }
    }
    __syncthreads();
#pragma unroll
    for (int fr = 0; fr < 2; ++fr) {
      const int s = w * 32 + fr * 16 + lr;
      v8bf ah, al;
#pragma unroll
      for (int e = 0; e < 8; ++e) {
        __bf16 h, l;
        split2(ct[lg * 8 + e][s], h, l);
        ah[e] = h;
        al[e] = l;
      }
#pragma unroll
      for (int fc = 0; fc < 2; ++fc) {
        acc[fr][fc] = MFMA16(ah, bhc[fc], acc[fr][fc], 0, 0, 0);
        acc[fr][fc] = MFMA16(ah, blc[fc], acc[fr][fc], 0, 0, 0);
        acc[fr][fc] = MFMA16(al, bhc[fc], acc[fr][fc], 0, 0, 0);
      }
    }
    if (it + 1 < NT) {
#pragma unroll
      for (int j = 0; j < 8; ++j) rc[j] = nc[j];
#pragma unroll
      for (int fc = 0; fc < 2; ++fc) {
        bhc[fc] = bhn[fc];
        blc[fc] = bln[fc];
      }
    }
  }
#pragma unroll
  for (int fr = 0; fr < 2; ++fr)
#pragma unroll
    for (int fc = 0; fc < 2; ++fc) {
      const int o = o0 + fc * 16 + lr;
      __bf16 hp[4];
#pragma unroll
      for (int r = 0; r < 4; ++r) {
        int s = w * 32 + fr * 16 + lg * 4 + r;
        __bf16 h, l;
        split2(acc[fr][fc][r], h, l);
        STh[((size_t)b * SLN + s) * IDF + o] = h;
        STl[((size_t)b * SLN + s) * IDF + o] = l;
        hp[r] = h;
      }
      *(v4bf*)(Shv + ((size_t)b * IDF + o) * SLN + w * 32 + fr * 16 + lg * 4) =
          (v4bf){hp[0], hp[1], hp[2], hp[3]};
    }
}

// -----------------------------------------------------------------------------
// K2 qk: L[s][q] = sum_i ST[s][i]*input[b][i][q]; mask; softmax over s;
// writes attn_out f32 and Ppv bf16 [b][q][s].  Tile 128s x 64q, grid (16,32).
// 2-phase reg-staged pipeline: loads(t+1) issued before compute(t).
// A (ST hi/lo) in LDS [128][32] with chunk-XOR swizzle p = c ^ ((r>>1)&3)
// (2-way banks on write and b128 read). input tile f32 LDS [32][66].
// -----------------------------------------------------------------------------
__global__ __launch_bounds__(256) void qk_k(const float* __restrict__ input,
                                            const __bf16* __restrict__ STh,
                                            const __bf16* __restrict__ STl,
                                            const int* __restrict__ mask,
                                            __bf16* __restrict__ Ppv,
                                            float* __restrict__ attn_out) {
  const int b = blockIdx.y, q0 = blockIdx.x * 64;
  const int t = threadIdx.x, w = t >> 6, lane = t & 63;
  const int lr = lane & 15, lg = lane >> 4;
  __shared__ __bf16 AhL[128][32];
  __shared__ __bf16 AlL[128][32];
  __shared__ __align__(16) float tiL[32][66];
  __shared__ float msk[SLN];
  if (t < SLN) msk[t] = -10000.0f * (float)mask[b * SLN + t];

  v4f acc[8];
#pragma unroll
  for (int fr = 0; fr < 8; ++fr) acc[fr] = (v4f){0.f, 0.f, 0.f, 0.f};

  // stage maps
  const int ra = t >> 1, ca0 = (t & 1) * 2;           // A: row s, logical chunks
  const int swA = (ra >> 1) & 3;
  const int pa0 = (ca0 ^ swA) * 8, pa1 = ((ca0 + 1) ^ swA) * 8;
  const int rb = t >> 3, cb = (t & 7) * 8;            // ti: row i-local, col f32
  const __bf16* pSTh = STh + ((size_t)b * SLN + ra) * IDF;
  const __bf16* pSTl = STl + ((size_t)b * SLN + ra) * IDF;
  const float*  pIn  = input + ((size_t)b * IDF + rb) * QLN + q0 + cb;

  uint4 rAh0, rAh1, rAl0, rAl1;
  float4 rT0, rT1;
  // prologue: tile 0
  rAh0 = *(const uint4*)(pSTh + ca0 * 8);
  rAh1 = *(const uint4*)(pSTh + ca0 * 8 + 8);
  rAl0 = *(const uint4*)(pSTl + ca0 * 8);
  rAl1 = *(const uint4*)(pSTl + ca0 * 8 + 8);
  rT0 = *(const float4*)(pIn);
  rT1 = *(const float4*)(pIn + 4);

#pragma unroll 2
  for (int it = 0; it < NT; ++it) {
    __syncthreads();
    *(uint4*)&AhL[ra][pa0] = rAh0;
    *(uint4*)&AhL[ra][pa1] = rAh1;
    *(uint4*)&AlL[ra][pa0] = rAl0;
    *(uint4*)&AlL[ra][pa1] = rAl1;
    *(float2*)&tiL[rb][cb]     = make_float2(rT0.x, rT0.y);
    *(float2*)&tiL[rb][cb + 2] = make_float2(rT0.z, rT0.w);
    *(float2*)&tiL[rb][cb + 4] = make_float2(rT1.x, rT1.y);
    *(float2*)&tiL[rb][cb + 6] = make_float2(rT1.z, rT1.w);

    uint4 nAh0, nAh1, nAl0, nAl1;
    float4 nT0, nT1;
    if (it + 1 < NT) {
      const int i0n = (it + 1) * 32;
      nAh0 = *(const uint4*)(pSTh + i0n + ca0 * 8);
      nAh1 = *(const uint4*)(pSTh + i0n + ca0 * 8 + 8);
      nAl0 = *(const uint4*)(pSTl + i0n + ca0 * 8);
      nAl1 = *(const uint4*)(pSTl + i0n + ca0 * 8 + 8);
      nT0 = *(const float4*)(pIn + (size_t)(it + 1) * 32 * QLN);
      nT1 = *(const float4*)(pIn + (size_t)(it + 1) * 32 * QLN + 4);
    }
    __syncthreads();

    // B-split from ti (2-way banks)
    v8bf bh, bl;
#pragma unroll
    for (int e = 0; e < 8; ++e) {
      __bf16 h, l;
      split2(tiL[lg * 8 + e][w * 16 + lr], h, l);
      bh[e] = h;
      bl[e] = l;
    }
#pragma unroll
    for (int fr = 0; fr < 8; ++fr) {
      const int r = fr * 16 + lr;
      const int p = (lg ^ ((r >> 1) & 3)) * 8;
      v8bf ah = *(const v8bf*)&AhL[r][p];
      v8bf al = *(const v8bf*)&AlL[r][p];
      acc[fr] = MFMA16(ah, bh, acc[fr], 0, 0, 0);
      acc[fr] = MFMA16(ah, bl, acc[fr], 0, 0, 0);
      acc[fr] = MFMA16(al, bh, acc[fr], 0, 0, 0);
    }
    if (it + 1 < NT) {
      rAh0 = nAh0; rAh1 = nAh1; rAl0 = nAl0; rAl1 = nAl1;
      rT0 = nT0; rT1 = nT1;
    }
  }

  // softmax over s (lane holds 32 s for one q)
  const int q = q0 + w * 16 + lr;
  float mx = -3.0e38f;
#pragma unroll
  for (int fr = 0; fr < 8; ++fr)
#pragma unroll
    for (int r = 0; r < 4; ++r) {
      acc[fr][r] += msk[fr * 16 + lg * 4 + r];
      mx = fmaxf(mx, acc[fr][r]);
    }
  mx = fmaxf(mx, __shfl_xor(mx, 16));
  mx = fmaxf(mx, __shfl_xor(mx, 32));
  float sum = 0.f;
#pragma unroll
  for (int fr = 0; fr < 8; ++fr)
#pragma unroll
    for (int r = 0; r < 4; ++r) {
      float e = __expf(acc[fr][r] - mx);
      acc[fr][r] = e;
      sum += e;
    }
  sum += __shfl_xor(sum, 16);
  sum += __shfl_xor(sum, 32);
  const float inv = 1.0f / sum;
#pragma unroll
  for (int fr = 0; fr < 8; ++fr) {
    __bf16 hp[4];
#pragma unroll
    for (int r = 0; r < 4; ++r) {
      float p = acc[fr][r] * inv;
      attn_out[((size_t)b * SLN + fr * 16 + lg * 4 + r) * QLN + q] = p;
      hp[r] = (__bf16)p;
    }
    *(v4bf*)(Ppv + ((size_t)b * QLN + q) * SLN + fr * 16 + lg * 4) =
        (v4bf){hp[0], hp[1], hp[2], hp[3]};
  }
}

// -----------------------------------------------------------------------------
// K3 pv: wc[i][q] = sum_s Shv[i][s] * P[q][s].  Grid (8q,6i,32b)=1536 blocks,
// 4 blocks/CU (LDS 34.8KB). P tile staged in LDS [128][136]; Shv fragments
// direct from L2 (196KB/batch, reused 8x); no barriers in the MFMA loop.
// -----------------------------------------------------------------------------
__global__ __launch_bounds__(256) void pv_k(const __bf16* __restrict__ Shv,
                                            const __bf16* __restrict__ Ppv,
                                            float* __restrict__ wc) {
  const int b = blockIdx.z, i0 = blockIdx.y * 128, q0 = blockIdx.x * 128;
  const int t = threadIdx.x, w = t >> 6, lane = t & 63;
  const int lr = lane & 15, lg = lane >> 4;
  __shared__ __align__(16) __bf16 PL[128][136];
  {
    const int pr = t >> 1, pc = (t & 1) * 64;
    const __bf16* src = Ppv + ((size_t)b * QLN + q0 + pr) * SLN + pc;
#pragma unroll
    for (int j = 0; j < 8; ++j)
      *(uint4*)&PL[pr][pc + j * 8] = *(const uint4*)(src + j * 8);
  }
  __syncthreads();
  v4f acc[2][8];
#pragma unroll
  for (int fr = 0; fr < 2; ++fr)
#pragma unroll
    for (int fc = 0; fc < 8; ++fc) acc[fr][fc] = (v4f){0.f, 0.f, 0.f, 0.f};
#pragma unroll
  for (int kt = 0; kt < 4; ++kt) {
    const int k0 = kt * 32 + lg * 8;
    v8bf a0 = *(const v8bf*)(Shv + ((size_t)b * IDF + i0 + w * 32 + lr) * SLN + k0);
    v8bf a1 = *(const v8bf*)(Shv + ((size_t)b * IDF + i0 + w * 32 + 16 + lr) * SLN + k0);
#pragma unroll
    for (int fc = 0; fc < 8; ++fc) {
      v8bf pb = *(const v8bf*)&PL[fc * 16 + lr][k0];
      acc[0][fc] = MFMA16(a0, pb, acc[0][fc], 0, 0, 0);
      acc[1][fc] = MFMA16(a1, pb, acc[1][fc], 0, 0, 0);
    }
  }
#pragma unroll
  for (int fr = 0; fr < 2; ++fr)
#pragma unroll
    for (int fc = 0; fc < 8; ++fc)
#pragma unroll
      for (int r = 0; r < 4; ++r)
        wc[((size_t)b * IDF + i0 + w * 32 + fr * 16 + lg * 4 + r) * QLN +
           q0 + fc * 16 + lr] = acc[fr][fc][r];
}

// -----------------------------------------------------------------------------
extern "C" void kernel_launch(void* const* d_in, const int* in_sizes, int n_in,
                              void* d_out, int out_size, void* d_ws, size_t ws_size,
                              hipStream_t stream) {
  const float* input   = (const float*)d_in[0];  // [B, IDF, 32, 32]
  const float* context = (const float*)d_in[1];  // [B, CDF, SL]
  const int*   mask    = (const int*)d_in[2];    // [B, SL]
  const float* w_conv  = (const float*)d_in[3];  // [IDF, CDF]

  float* out      = (float*)d_out;
  float* wc       = out;                          // [B, IDF, QL]
  float* attn_out = out + (size_t)NB * IDF * QLN; // [B, SL, QL]

  // ws layout (bf16 elems). Ppv aliases Wh/Wl (dead after proj_k):
  //   [0 .. 4.19M)   Ppv [b][q][s]        (Wh at 0, Wl at 589824 inside)
  //   [4.19M ..)     STh, STl [b][s][768], Shv [b][i][s]
  // total = 27,262,976 B  (< 29,360,128 proven available)
  __bf16* wsb = (__bf16*)d_ws;
  const size_t WE = (size_t)IDF * IDF;       // 589,824
  const size_t SE = (size_t)NB * SLN * IDF;  // 3,145,728
  const size_t PE = (size_t)NB * QLN * SLN;  // 4,194,304
  __bf16* Ppv = wsb;
  __bf16* Wh  = wsb;
  __bf16* Wl  = Wh + WE;
  __bf16* STh = wsb + PE;
  __bf16* STl = STh + SE;
  __bf16* Shv = STl + SE;

  prep_w<<<576, 256, 0, stream>>>(w_conv, Wh, Wl);
  proj_k<<<dim3(24, NB), 256, 0, stream>>>(context, Wh, Wl, STh, STl, Shv);
  qk_k<<<dim3(16, NB), 256, 0, stream>>>(input, STh, STl, mask, Ppv, attn_out);
  pv_k<<<dim3(8, 6, NB), 256, 0, stream>>>(Shv, Ppv, wc);
}